// Round 1
// baseline (1054.779 us; speedup 1.0000x reference)
//
#include <hip/hip_runtime.h>

#define TWO_PI 6.283185307179586f

// Problem constants
#define HH 128      // H
#define WW 128      // W
#define FN 256      // padded FFT size (2H)
#define NF 129      // FN/2+1 vertical frequency bins
#define CC 96
#define BB 16

__device__ __forceinline__ float2 cmul(float2 a, float2 b){
  return make_float2(a.x*b.x - a.y*b.y, a.x*b.y + a.y*b.x);
}
__device__ __forceinline__ float2 cadd(float2 a, float2 b){ return make_float2(a.x+b.x, a.y+b.y); }
__device__ __forceinline__ float2 csub(float2 a, float2 b){ return make_float2(a.x-b.x, a.y-b.y); }

// ---------------------------------------------------------------------------
// Kernel A: generate implicit kernel k[c][p][q] from the tiny MLP.
// pe = (p/127, q/127); hid = relu(pe@W1 + b1) (16); k = hid@W2 + b2
// ---------------------------------------------------------------------------
__global__ __launch_bounds__(256) void gen_k(const float* __restrict__ W1,
                                             const float* __restrict__ b1,
                                             const float* __restrict__ W2,
                                             const float* __restrict__ b2,
                                             float* __restrict__ kout){
  int gid = blockIdx.x * 256 + threadIdx.x;      // c*16384 + p*128 + q
  int q = gid & 127;
  int p = (gid >> 7) & 127;
  int c = gid >> 14;
  float gy = p * (1.0f / 127.0f);
  float gx = q * (1.0f / 127.0f);
  float acc = b2[c];
#pragma unroll
  for (int h = 0; h < 16; ++h){
    float hv = gy * W1[h] + gx * W1[16 + h] + b1[h];
    hv = fmaxf(hv, 0.0f);
    acc += hv * W2[h * 96 + c];
  }
  kout[gid] = acc;
}

// ---------------------------------------------------------------------------
// Kernel B: vertical r2c 256-pt FFT (zero-padded from 128 real rows).
// in : real [img][128][128]
// out: complex [img][129][128]   (Hermitian half)
// One block = one image x 32 columns. LDS: 256x32 complex = 64 KB.
// ---------------------------------------------------------------------------
__global__ __launch_bounds__(256) void vfft_r2c(const float* __restrict__ in,
                                                float2* __restrict__ out){
  __shared__ float2 buf[256][32];
  __shared__ float2 tw[128];
  int t = threadIdx.x;
  int img = blockIdx.x >> 2;
  int q0 = (blockIdx.x & 3) * 32;
  if (t < 128){
    float s, c;
    sincosf(-TWO_PI * (float)t / 256.0f, &s, &c);
    tw[t] = make_float2(c, s);
  }
  int qq = t & 31, pr = t >> 5;
  const float* ip = in + (size_t)img * (HH * WW) + q0;
#pragma unroll
  for (int it = 0; it < 16; ++it){
    int p = it * 8 + pr;
    buf[p][qq] = make_float2(ip[p * WW + qq], 0.0f);
    buf[p + 128][qq] = make_float2(0.0f, 0.0f);
  }
  __syncthreads();
  // bit-reversal permutation (per column)
  for (int it = 0; it < 32; ++it){
    int p = pr * 32 + it;
    int rp = __brev((unsigned)p) >> 24;
    if (p < rp){ float2 a = buf[p][qq]; buf[p][qq] = buf[rp][qq]; buf[rp][qq] = a; }
  }
  __syncthreads();
  // 8 radix-2 stages (DIT, natural output)
  for (int s = 0; s < 8; ++s){
    int half = 1 << s;
    for (int bi = 0; bi < 16; ++bi){
      int b = pr + 8 * bi;                 // 128 butterflies / column
      int k = b & (half - 1);
      int g = (b >> s) << (s + 1);
      int i1 = g + k, i2 = i1 + half;
      float2 w = tw[k << (7 - s)];
      float2 u = buf[i1][qq];
      float2 v = cmul(w, buf[i2][qq]);
      buf[i1][qq] = cadd(u, v);
      buf[i2][qq] = csub(u, v);
    }
    __syncthreads();
  }
  // store Hermitian half (u in [0,129))
  float2* op = out + (size_t)img * (NF * WW) + q0;
  for (int it = 0; it < 17; ++it){
    int u = it * 8 + pr;
    if (u < NF) op[(size_t)u * WW + qq] = buf[u][qq];
  }
}

// ---------------------------------------------------------------------------
// Shared 256-pt in-LDS FFT over row r of buf[8][256], 32 lanes per row.
// Contains block-wide barriers -> must be called uniformly by all 256 threads.
// ---------------------------------------------------------------------------
__device__ __forceinline__ void fft256_row(float2 (*buf)[256], const float2* tw,
                                           int r, int lane32){
  for (int i = 0; i < 8; ++i){
    int p = lane32 + 32 * i;
    int rp = __brev((unsigned)p) >> 24;
    if (p < rp){ float2 a = buf[r][p]; buf[r][p] = buf[r][rp]; buf[r][rp] = a; }
  }
  __syncthreads();
  for (int s = 0; s < 8; ++s){
    int half = 1 << s;
    for (int bi = 0; bi < 4; ++bi){
      int b = lane32 + 32 * bi;
      int k = b & (half - 1);
      int g = (b >> s) << (s + 1);
      int i1 = g + k, i2 = i1 + half;
      float2 w = tw[k << (7 - s)];
      float2 u = buf[r][i1];
      float2 v = cmul(w, buf[r][i2]);
      buf[r][i1] = cadd(u, v);
      buf[r][i2] = csub(u, v);
    }
    __syncthreads();
  }
}

// ---------------------------------------------------------------------------
// Kernel D: row FFT of Kcol -> Khat (forward only, full 256 output).
// Kcol: [c][u][q<128] complex ; Khat: [c][u][v<256] complex. 8 rows/block.
// ---------------------------------------------------------------------------
__global__ __launch_bounds__(256) void kfft_row(const float2* __restrict__ Kcol,
                                                float2* __restrict__ Khat,
                                                int nrows){
  __shared__ float2 buf[8][256];
  __shared__ float2 twf[128];
  int t = threadIdx.x;
  if (t < 128){
    float s, c; sincosf(-TWO_PI * (float)t / 256.0f, &s, &c);
    twf[t] = make_float2(c, s);
  }
  int r = t >> 5, lane32 = t & 31;
  int rowid = blockIdx.x * 8 + r;
  bool active = rowid < nrows;
  if (active){
    const float2* src = Kcol + (size_t)rowid * WW;
    for (int i = 0; i < 4; ++i){
      int v = lane32 + 32 * i;
      buf[r][v] = src[v];
      buf[r][v + 128] = make_float2(0.0f, 0.0f);
    }
  }
  __syncthreads();
  fft256_row(buf, twf, r, lane32);
  if (active){
    float2* dst = Khat + (size_t)rowid * FN;
    for (int i = 0; i < 8; ++i){
      int v = lane32 + 32 * i;
      dst[v] = buf[r][v];
    }
  }
}

// ---------------------------------------------------------------------------
// Kernel C: fused row stage. For each (img_local, u) row of A:
//   fwd FFT256 (zero-padded) -> multiply by Khat[c][u][:] -> inv FFT256
//   -> keep first 128, write back in place.
// ---------------------------------------------------------------------------
__global__ __launch_bounds__(256) void rowfft_mul_ifft(float2* __restrict__ A,
                                                       const float2* __restrict__ Khat,
                                                       int nrows){
  __shared__ float2 buf[8][256];
  __shared__ float2 twf[128];
  __shared__ float2 twi[128];
  int t = threadIdx.x;
  if (t < 128){
    float s, c; sincosf(-TWO_PI * (float)t / 256.0f, &s, &c);
    twf[t] = make_float2(c, s);
  } else {
    int k = t - 128;
    float s, c; sincosf(TWO_PI * (float)k / 256.0f, &s, &c);
    twi[k] = make_float2(c, s);
  }
  int r = t >> 5, lane32 = t & 31;
  int rowid = blockIdx.x * 8 + r;
  bool active = rowid < nrows;
  size_t base = (size_t)rowid * WW;
  int u = rowid % NF;
  int c = (rowid / NF) % CC;
  if (active){
    for (int i = 0; i < 4; ++i){
      int v = lane32 + 32 * i;
      buf[r][v] = A[base + v];
      buf[r][v + 128] = make_float2(0.0f, 0.0f);
    }
  }
  __syncthreads();
  fft256_row(buf, twf, r, lane32);          // forward, natural order out
  if (active){
    const float2* kp = Khat + ((size_t)c * NF + u) * FN;
    for (int i = 0; i < 8; ++i){
      int v = lane32 + 32 * i;
      buf[r][v] = cmul(buf[r][v], kp[v]);
    }
  }
  __syncthreads();
  fft256_row(buf, twi, r, lane32);          // unnormalized inverse
  if (active){
    for (int i = 0; i < 4; ++i){
      int v = lane32 + 32 * i;
      A[base + v] = buf[r][v];
    }
  }
}

// ---------------------------------------------------------------------------
// Kernel E: vertical c2r inverse (Hermitian extend 129->256 in LDS) + crop
// + residual add. One block = one image x 32 columns.
// ---------------------------------------------------------------------------
__global__ __launch_bounds__(256) void vifft_c2r_add(const float2* __restrict__ Cbuf,
                                                     const float* __restrict__ xin,
                                                     float* __restrict__ yout){
  __shared__ float2 buf[256][32];
  __shared__ float2 tw[128];
  int t = threadIdx.x;
  int img = blockIdx.x >> 2;
  int q0 = (blockIdx.x & 3) * 32;
  if (t < 128){
    float s, c; sincosf(TWO_PI * (float)t / 256.0f, &s, &c);  // inverse twiddles
    tw[t] = make_float2(c, s);
  }
  int qq = t & 31, pr = t >> 5;
  const float2* ip = Cbuf + (size_t)img * (NF * WW) + q0;
  for (int it = 0; it < 17; ++it){
    int u = it * 8 + pr;
    if (u < NF) buf[u][qq] = ip[(size_t)u * WW + qq];
  }
  __syncthreads();
  // Hermitian extension: buf[u] = conj(buf[256-u]) for u in (128,256)
  for (int it = 0; it < 16; ++it){
    int u = 129 + it * 8 + pr;
    if (u < 256){
      float2 a = buf[256 - u][qq];
      buf[u][qq] = make_float2(a.x, -a.y);
    }
  }
  __syncthreads();
  for (int it = 0; it < 32; ++it){
    int p = pr * 32 + it;
    int rp = __brev((unsigned)p) >> 24;
    if (p < rp){ float2 a = buf[p][qq]; buf[p][qq] = buf[rp][qq]; buf[rp][qq] = a; }
  }
  __syncthreads();
  for (int s = 0; s < 8; ++s){
    int half = 1 << s;
    for (int bi = 0; bi < 16; ++bi){
      int b = pr + 8 * bi;
      int k = b & (half - 1);
      int g = (b >> s) << (s + 1);
      int i1 = g + k, i2 = i1 + half;
      float2 w = tw[k << (7 - s)];
      float2 u = buf[i1][qq];
      float2 v = cmul(w, buf[i2][qq]);
      buf[i1][qq] = cadd(u, v);
      buf[i2][qq] = csub(u, v);
    }
    __syncthreads();
  }
  // y = Re(first 128 rows) + x   (no normalization: matches norm='forward')
  const float* xp = xin + (size_t)img * (HH * WW) + q0;
  float* yp = yout + (size_t)img * (HH * WW) + q0;
  for (int it = 0; it < 16; ++it){
    int i = it * 8 + pr;
    yp[i * WW + qq] = buf[i][qq].x + xp[i * WW + qq];
  }
}

// ---------------------------------------------------------------------------
// Host launcher
// ---------------------------------------------------------------------------
extern "C" void kernel_launch(void* const* d_in, const int* in_sizes, int n_in,
                              void* d_out, int out_size, void* d_ws, size_t ws_size,
                              hipStream_t stream) {
  const float* x  = (const float*)d_in[0];
  const float* W1 = (const float*)d_in[1];
  const float* b1 = (const float*)d_in[2];
  const float* W2 = (const float*)d_in[3];
  const float* b2 = (const float*)d_in[4];
  float* out = (float*)d_out;

  char* ws = (char*)d_ws;
  size_t off = 0;
  auto alloc = [&](size_t bytes) -> void* {
    void* p = ws + off;
    off += (bytes + 255) & ~(size_t)255;
    return p;
  };

  float2* Khat  = (float2*)alloc((size_t)CC * NF * FN * sizeof(float2)); // 25.4 MB
  float*  kreal = (float*) alloc((size_t)CC * HH * WW * sizeof(float));  //  6.3 MB
  float2* Kcol  = (float2*)alloc((size_t)CC * NF * WW * sizeof(float2)); // 12.7 MB
  size_t fixed = off;

  // adaptive batch chunking of the A workspace vs ws_size
  int chunkB = 16;
  while (chunkB > 1 &&
         fixed + (size_t)chunkB * CC * NF * WW * sizeof(float2) > ws_size)
    chunkB >>= 1;
  float2* A = (float2*)alloc((size_t)chunkB * CC * NF * WW * sizeof(float2));

  // 1) implicit kernel -> spectrum Khat
  gen_k<<<(CC * HH * WW) / 256, 256, 0, stream>>>(W1, b1, W2, b2, kreal);
  vfft_r2c<<<CC * 4, 256, 0, stream>>>(kreal, Kcol);
  kfft_row<<<(CC * NF + 7) / 8, 256, 0, stream>>>(Kcol, Khat, CC * NF);

  // 2) per batch-chunk: vertical FFT -> fused row conv -> vertical inverse + add
  for (int b0 = 0; b0 < BB; b0 += chunkB){
    int nimg = chunkB * CC;
    const float* xc = x   + (size_t)b0 * CC * HH * WW;
    float*       yc = out + (size_t)b0 * CC * HH * WW;
    vfft_r2c<<<nimg * 4, 256, 0, stream>>>(xc, A);
    rowfft_mul_ifft<<<(nimg * NF + 7) / 8, 256, 0, stream>>>(A, Khat, nimg * NF);
    vifft_c2r_add<<<nimg * 4, 256, 0, stream>>>(A, xc, yc);
  }
}

// Round 2
// 840.116 us; speedup vs baseline: 1.2555x; 1.2555x over previous
//
#include <hip/hip_runtime.h>

#define TWO_PI 6.283185307179586f
#define PI_F   3.14159265358979f

// Problem constants
#define HH 128      // H
#define WW 128      // W
#define FN 256      // padded FFT size (2H)
#define NF 129      // FN/2+1 vertical frequency bins
#define CC 96
#define BB 16

__device__ __forceinline__ float2 cmul(float2 a, float2 b){
  return make_float2(a.x*b.x - a.y*b.y, a.x*b.y + a.y*b.x);
}
__device__ __forceinline__ float2 cadd(float2 a, float2 b){ return make_float2(a.x+b.x, a.y+b.y); }
__device__ __forceinline__ float2 csub(float2 a, float2 b){ return make_float2(a.x-b.x, a.y-b.y); }
__device__ __forceinline__ float2 shflx(float2 v, int m){
  float2 r; r.x = __shfl_xor(v.x, m, 64); r.y = __shfl_xor(v.y, m, 64); return r;
}

// ---------------------------------------------------------------------------
// Wave-resident 256-pt FFT: lane l holds positions l, l+64, l+128, l+192.
// Forward = DIF (natural in -> bit-reversed positions out), inverse = DIT
// (bit-reversed in -> natural out). No reordering anywhere; the pointwise
// product pairs identically because Khat is produced by the same DIF.
// ---------------------------------------------------------------------------
struct Tw {
  float2 w128a, w128b, w64;
  float2 wc[5];   // cross-lane twiddles for h = 32,16,8,4,2  (h=1 is w=1)
};

__device__ __forceinline__ void tw_init(Tw& t, int l){
  float s, c;
  sincosf(-TWO_PI * (float)l * (1.0f/256.0f), &s, &c);
  t.w128a = make_float2(c, s);                 // W256^l
  t.w128b = make_float2(s, -c);                // W256^(l+64) = w128a * (-i)
  t.w64   = make_float2(c*c - s*s, 2.0f*c*s);  // W256^(2l)
  const int hs[5] = {32,16,8,4,2};
#pragma unroll
  for (int i = 0; i < 5; ++i){
    int h = hs[i];
    float ang = -PI_F * (float)(l & (h-1)) / (float)h;   // exp(-2pi*i*k/(2h))
    sincosf(ang, &s, &c);
    t.wc[i] = make_float2(c, s);
  }
}

// forward, input zero-padded (positions 128..255 == 0): only x0,x1 given.
__device__ __forceinline__ void fft256_fwd_padded(float2& x0, float2& x1,
                                                  float2& x2, float2& x3,
                                                  const Tw& t, int l){
  // stage h=128 (zero upper half): u'=u, v'=u*w
  x2 = cmul(x0, t.w128a);
  x3 = cmul(x1, t.w128b);
  // stage h=64
  float2 a = x0, b = x1;
  x0 = cadd(a, b); x1 = cmul(csub(a, b), t.w64);
  a = x2; b = x3;
  x2 = cadd(a, b); x3 = cmul(csub(a, b), t.w64);
  // cross-lane stages h=32..2
  const int hs[5] = {32,16,8,4,2};
#pragma unroll
  for (int i = 0; i < 5; ++i){
    int h = hs[i];
    bool up = (l & h) == 0;
    float2 w = t.wc[i], o;
    o = shflx(x0, h); x0 = up ? cadd(x0, o) : cmul(csub(o, x0), w);
    o = shflx(x1, h); x1 = up ? cadd(x1, o) : cmul(csub(o, x1), w);
    o = shflx(x2, h); x2 = up ? cadd(x2, o) : cmul(csub(o, x2), w);
    o = shflx(x3, h); x3 = up ? cadd(x3, o) : cmul(csub(o, x3), w);
  }
  // h=1: w == 1
  {
    bool up = (l & 1) == 0;
    float2 o;
    o = shflx(x0, 1); x0 = up ? cadd(x0, o) : csub(o, x0);
    o = shflx(x1, 1); x1 = up ? cadd(x1, o) : csub(o, x1);
    o = shflx(x2, 1); x2 = up ? cadd(x2, o) : csub(o, x2);
    o = shflx(x3, 1); x3 = up ? cadd(x3, o) : csub(o, x3);
  }
}

// inverse (unnormalized, conj twiddles), bit-reversed input, natural output;
// only positions 0..127 (x0,x1) are produced (crop fused into last stage).
__device__ __forceinline__ void fft256_inv_crop(float2& x0, float2& x1,
                                                float2& x2, float2& x3,
                                                const Tw& t, int l){
  // h=1 (w == 1)
  {
    bool up = (l & 1) == 0;
    float2 o;
    o = shflx(x0, 1); x0 = up ? cadd(x0, o) : csub(o, x0);
    o = shflx(x1, 1); x1 = up ? cadd(x1, o) : csub(o, x1);
    o = shflx(x2, 1); x2 = up ? cadd(x2, o) : csub(o, x2);
    o = shflx(x3, 1); x3 = up ? cadd(x3, o) : csub(o, x3);
  }
  // h=2..32 : DIT butterfly u' = u + w*v ; v' = u - w*v  (w = conj(fwd))
  const int hs[5] = {32,16,8,4,2};
#pragma unroll
  for (int i = 4; i >= 0; --i){
    int h = hs[i];
    bool up = (l & h) == 0;
    float2 w = make_float2(t.wc[i].x, -t.wc[i].y);
    float2 o;
    o = shflx(x0, h); x0 = up ? cadd(x0, cmul(w, o)) : csub(o, cmul(w, x0));
    o = shflx(x1, h); x1 = up ? cadd(x1, cmul(w, o)) : csub(o, cmul(w, x1));
    o = shflx(x2, h); x2 = up ? cadd(x2, cmul(w, o)) : csub(o, cmul(w, x2));
    o = shflx(x3, h); x3 = up ? cadd(x3, cmul(w, o)) : csub(o, cmul(w, x3));
  }
  // h=64 in-lane
  {
    float2 w = make_float2(t.w64.x, -t.w64.y);
    float2 t0 = cmul(w, x1); x1 = csub(x0, t0); x0 = cadd(x0, t0);
    float2 t1 = cmul(w, x3); x3 = csub(x2, t1); x2 = cadd(x2, t1);
  }
  // h=128 in-lane, crop: keep only positions 0..127
  {
    float2 wa = make_float2(t.w128a.x, -t.w128a.y);
    float2 wb = make_float2(t.w128b.x, -t.w128b.y);
    x0 = cadd(x0, cmul(wa, x2));
    x1 = cadd(x1, cmul(wb, x3));
  }
}

// ---------------------------------------------------------------------------
// Kernel A: generate implicit kernel k[c][p][q] from the tiny MLP.
// ---------------------------------------------------------------------------
__global__ __launch_bounds__(256) void gen_k(const float* __restrict__ W1,
                                             const float* __restrict__ b1,
                                             const float* __restrict__ W2,
                                             const float* __restrict__ b2,
                                             float* __restrict__ kout){
  int gid = blockIdx.x * 256 + threadIdx.x;      // c*16384 + p*128 + q
  int q = gid & 127;
  int p = (gid >> 7) & 127;
  int c = gid >> 14;
  float gy = p * (1.0f / 127.0f);
  float gx = q * (1.0f / 127.0f);
  float acc = b2[c];
#pragma unroll
  for (int h = 0; h < 16; ++h){
    float hv = gy * W1[h] + gx * W1[16 + h] + b1[h];
    hv = fmaxf(hv, 0.0f);
    acc += hv * W2[h * 96 + c];
  }
  kout[gid] = acc;
}

// ---------------------------------------------------------------------------
// Kernel B: vertical r2c 256-pt FFT (zero-padded from 128 real rows).
// (unchanged from R0 — LDS radix-2; rewrite planned next round)
// ---------------------------------------------------------------------------
__global__ __launch_bounds__(256) void vfft_r2c(const float* __restrict__ in,
                                                float2* __restrict__ out){
  __shared__ float2 buf[256][32];
  __shared__ float2 tw[128];
  int t = threadIdx.x;
  int img = blockIdx.x >> 2;
  int q0 = (blockIdx.x & 3) * 32;
  if (t < 128){
    float s, c;
    sincosf(-TWO_PI * (float)t / 256.0f, &s, &c);
    tw[t] = make_float2(c, s);
  }
  int qq = t & 31, pr = t >> 5;
  const float* ip = in + (size_t)img * (HH * WW) + q0;
#pragma unroll
  for (int it = 0; it < 16; ++it){
    int p = it * 8 + pr;
    buf[p][qq] = make_float2(ip[p * WW + qq], 0.0f);
    buf[p + 128][qq] = make_float2(0.0f, 0.0f);
  }
  __syncthreads();
  for (int it = 0; it < 32; ++it){
    int p = pr * 32 + it;
    int rp = __brev((unsigned)p) >> 24;
    if (p < rp){ float2 a = buf[p][qq]; buf[p][qq] = buf[rp][qq]; buf[rp][qq] = a; }
  }
  __syncthreads();
  for (int s = 0; s < 8; ++s){
    int half = 1 << s;
    for (int bi = 0; bi < 16; ++bi){
      int b = pr + 8 * bi;
      int k = b & (half - 1);
      int g = (b >> s) << (s + 1);
      int i1 = g + k, i2 = i1 + half;
      float2 w = tw[k << (7 - s)];
      float2 u = buf[i1][qq];
      float2 v = cmul(w, buf[i2][qq]);
      buf[i1][qq] = cadd(u, v);
      buf[i2][qq] = csub(u, v);
    }
    __syncthreads();
  }
  float2* op = out + (size_t)img * (NF * WW) + q0;
  for (int it = 0; it < 17; ++it){
    int u = it * 8 + pr;
    if (u < NF) op[(size_t)u * WW + qq] = buf[u][qq];
  }
}

// ---------------------------------------------------------------------------
// Kernel D: Khat row spectra via the wave DIF (bit-reversed v positions,
// matching rowconv_wave exactly). One row per wave.
// ---------------------------------------------------------------------------
__global__ __launch_bounds__(256) void kfft_wave(const float2* __restrict__ Kcol,
                                                 float2* __restrict__ Khat,
                                                 int nrows){
  int l = threadIdx.x & 63;
  int wid = (blockIdx.x * 256 + threadIdx.x) >> 6;
  int nw  = gridDim.x * 4;
  Tw t; tw_init(t, l);
  for (int row = wid; row < nrows; row += nw){
    const float2* src = Kcol + (size_t)row * WW;
    float2 x0 = src[l];
    float2 x1 = src[64 + l];
    float2 x2, x3;
    fft256_fwd_padded(x0, x1, x2, x3, t, l);
    float2* dst = Khat + (size_t)row * FN;
    dst[l]       = x0;
    dst[64 + l]  = x1;
    dst[128 + l] = x2;
    dst[192 + l] = x3;
  }
}

// ---------------------------------------------------------------------------
// Kernel C: fused row stage, wave-resident. Per (img_local, u) row:
// DIF fwd (padded) -> x Khat (bit-reversed positions) -> DIT inv + crop.
// No LDS, no barriers; grid-stride over rows, one row per wave.
// ---------------------------------------------------------------------------
__global__ __launch_bounds__(256) void rowconv_wave(float2* __restrict__ A,
                                                    const float2* __restrict__ Khat,
                                                    int nrows){
  int l = threadIdx.x & 63;
  int wid = (blockIdx.x * 256 + threadIdx.x) >> 6;
  int nw  = gridDim.x * 4;
  Tw t; tw_init(t, l);
  for (int row = wid; row < nrows; row += nw){
    size_t base = (size_t)row * WW;
    float2 x0 = A[base + l];
    float2 x1 = A[base + 64 + l];
    float2 x2, x3;
    fft256_fwd_padded(x0, x1, x2, x3, t, l);
    int img = row / NF;
    int u   = row - img * NF;
    int c   = img % CC;
    const float2* kp = Khat + ((size_t)c * NF + u) * FN;
    x0 = cmul(x0, kp[l]);
    x1 = cmul(x1, kp[64 + l]);
    x2 = cmul(x2, kp[128 + l]);
    x3 = cmul(x3, kp[192 + l]);
    fft256_inv_crop(x0, x1, x2, x3, t, l);
    A[base + l]      = x0;
    A[base + 64 + l] = x1;
  }
}

// ---------------------------------------------------------------------------
// Kernel E: vertical c2r inverse + crop + residual add.
// (unchanged from R0)
// ---------------------------------------------------------------------------
__global__ __launch_bounds__(256) void vifft_c2r_add(const float2* __restrict__ Cbuf,
                                                     const float* __restrict__ xin,
                                                     float* __restrict__ yout){
  __shared__ float2 buf[256][32];
  __shared__ float2 tw[128];
  int t = threadIdx.x;
  int img = blockIdx.x >> 2;
  int q0 = (blockIdx.x & 3) * 32;
  if (t < 128){
    float s, c; sincosf(TWO_PI * (float)t / 256.0f, &s, &c);
    tw[t] = make_float2(c, s);
  }
  int qq = t & 31, pr = t >> 5;
  const float2* ip = Cbuf + (size_t)img * (NF * WW) + q0;
  for (int it = 0; it < 17; ++it){
    int u = it * 8 + pr;
    if (u < NF) buf[u][qq] = ip[(size_t)u * WW + qq];
  }
  __syncthreads();
  for (int it = 0; it < 16; ++it){
    int u = 129 + it * 8 + pr;
    if (u < 256){
      float2 a = buf[256 - u][qq];
      buf[u][qq] = make_float2(a.x, -a.y);
    }
  }
  __syncthreads();
  for (int it = 0; it < 32; ++it){
    int p = pr * 32 + it;
    int rp = __brev((unsigned)p) >> 24;
    if (p < rp){ float2 a = buf[p][qq]; buf[p][qq] = buf[rp][qq]; buf[rp][qq] = a; }
  }
  __syncthreads();
  for (int s = 0; s < 8; ++s){
    int half = 1 << s;
    for (int bi = 0; bi < 16; ++bi){
      int b = pr + 8 * bi;
      int k = b & (half - 1);
      int g = (b >> s) << (s + 1);
      int i1 = g + k, i2 = i1 + half;
      float2 w = tw[k << (7 - s)];
      float2 u = buf[i1][qq];
      float2 v = cmul(w, buf[i2][qq]);
      buf[i1][qq] = cadd(u, v);
      buf[i2][qq] = csub(u, v);
    }
    __syncthreads();
  }
  const float* xp = xin + (size_t)img * (HH * WW) + q0;
  float* yp = yout + (size_t)img * (HH * WW) + q0;
  for (int it = 0; it < 16; ++it){
    int i = it * 8 + pr;
    yp[i * WW + qq] = buf[i][qq].x + xp[i * WW + qq];
  }
}

// ---------------------------------------------------------------------------
// Host launcher
// ---------------------------------------------------------------------------
extern "C" void kernel_launch(void* const* d_in, const int* in_sizes, int n_in,
                              void* d_out, int out_size, void* d_ws, size_t ws_size,
                              hipStream_t stream) {
  const float* x  = (const float*)d_in[0];
  const float* W1 = (const float*)d_in[1];
  const float* b1 = (const float*)d_in[2];
  const float* W2 = (const float*)d_in[3];
  const float* b2 = (const float*)d_in[4];
  float* out = (float*)d_out;

  char* ws = (char*)d_ws;
  size_t off = 0;
  auto alloc = [&](size_t bytes) -> void* {
    void* p = ws + off;
    off += (bytes + 255) & ~(size_t)255;
    return p;
  };

  float2* Khat  = (float2*)alloc((size_t)CC * NF * FN * sizeof(float2)); // 25.4 MB
  float*  kreal = (float*) alloc((size_t)CC * HH * WW * sizeof(float));  //  6.3 MB
  float2* Kcol  = (float2*)alloc((size_t)CC * NF * WW * sizeof(float2)); // 12.7 MB
  size_t fixed = off;

  int chunkB = 16;
  while (chunkB > 1 &&
         fixed + (size_t)chunkB * CC * NF * WW * sizeof(float2) > ws_size)
    chunkB >>= 1;
  float2* A = (float2*)alloc((size_t)chunkB * CC * NF * WW * sizeof(float2));

  // 1) implicit kernel -> spectrum Khat (bit-reversed v positions)
  gen_k<<<(CC * HH * WW) / 256, 256, 0, stream>>>(W1, b1, W2, b2, kreal);
  vfft_r2c<<<CC * 4, 256, 0, stream>>>(kreal, Kcol);
  {
    int nrows = CC * NF;
    int blocks = (nrows + 3) / 4;
    kfft_wave<<<blocks, 256, 0, stream>>>(Kcol, Khat, nrows);
  }

  // 2) per batch-chunk: vertical FFT -> fused row conv -> vertical inverse+add
  for (int b0 = 0; b0 < BB; b0 += chunkB){
    int nimg = chunkB * CC;
    const float* xc = x   + (size_t)b0 * CC * HH * WW;
    float*       yc = out + (size_t)b0 * CC * HH * WW;
    vfft_r2c<<<nimg * 4, 256, 0, stream>>>(xc, A);
    {
      int nrows = nimg * NF;
      int blocks = 8192;
      if (blocks * 4 > nrows) blocks = (nrows + 3) / 4;
      rowconv_wave<<<blocks, 256, 0, stream>>>(A, Khat, nrows);
    }
    vifft_c2r_add<<<nimg * 4, 256, 0, stream>>>(A, xc, yc);
  }
}

// Round 3
// 682.867 us; speedup vs baseline: 1.5446x; 1.2303x over previous
//
#include <hip/hip_runtime.h>
#include <hip/hip_fp16.h>

#define TWO_PI 6.283185307179586f
#define PI_F   3.14159265358979f

// Problem constants
#define HH 128      // H
#define WW 128      // W
#define FN 256      // padded FFT size (2H)
#define NF 129      // FN/2+1 vertical frequency bins
#define CC 96
#define BB 16

#define SCL_DN 0.0009765625f   // 2^-10 : scale on row-conv output before fp16 store
#define SCL_UP 1024.0f

__device__ __forceinline__ float2 cmul(float2 a, float2 b){
  return make_float2(a.x*b.x - a.y*b.y, a.x*b.y + a.y*b.x);
}
__device__ __forceinline__ float2 cadd(float2 a, float2 b){ return make_float2(a.x+b.x, a.y+b.y); }
__device__ __forceinline__ float2 csub(float2 a, float2 b){ return make_float2(a.x-b.x, a.y-b.y); }
__device__ __forceinline__ float2 shflx(float2 v, int m){
  float2 r; r.x = __shfl_xor(v.x, m, 64); r.y = __shfl_xor(v.y, m, 64); return r;
}
__device__ __forceinline__ unsigned short f2h(float v){ return __half_as_ushort(__float2half(v)); }
__device__ __forceinline__ float h2f(unsigned short u){ return __half2float(__ushort_as_half(u)); }

// ---------------------------------------------------------------------------
// Wave-resident 256-pt FFT (verified R1/R2): lane l holds positions
// l, l+64, l+128, l+192. Forward = DIF (natural in -> bit-reversed positions
// out; position j holds natural bin br8(j)). Inverse = DIT (bit-reversed in,
// natural out, crop to 0..127).
// ---------------------------------------------------------------------------
struct Tw {
  float2 w128a, w128b, w64;
  float2 wc[5];   // cross-lane twiddles for h = 32,16,8,4,2
};

__device__ __forceinline__ void tw_init(Tw& t, int l){
  float s, c;
  sincosf(-TWO_PI * (float)l * (1.0f/256.0f), &s, &c);
  t.w128a = make_float2(c, s);                 // W256^l
  t.w128b = make_float2(s, -c);                // W256^(l+64)
  t.w64   = make_float2(c*c - s*s, 2.0f*c*s);  // W256^(2l)
  const int hs[5] = {32,16,8,4,2};
#pragma unroll
  for (int i = 0; i < 5; ++i){
    int h = hs[i];
    float ang = -PI_F * (float)(l & (h-1)) / (float)h;
    sincosf(ang, &s, &c);
    t.wc[i] = make_float2(c, s);
  }
}

__device__ __forceinline__ void fft256_fwd_padded(float2& x0, float2& x1,
                                                  float2& x2, float2& x3,
                                                  const Tw& t, int l){
  x2 = cmul(x0, t.w128a);
  x3 = cmul(x1, t.w128b);
  float2 a = x0, b = x1;
  x0 = cadd(a, b); x1 = cmul(csub(a, b), t.w64);
  a = x2; b = x3;
  x2 = cadd(a, b); x3 = cmul(csub(a, b), t.w64);
  const int hs[5] = {32,16,8,4,2};
#pragma unroll
  for (int i = 0; i < 5; ++i){
    int h = hs[i];
    bool up = (l & h) == 0;
    float2 w = t.wc[i], o;
    o = shflx(x0, h); x0 = up ? cadd(x0, o) : cmul(csub(o, x0), w);
    o = shflx(x1, h); x1 = up ? cadd(x1, o) : cmul(csub(o, x1), w);
    o = shflx(x2, h); x2 = up ? cadd(x2, o) : cmul(csub(o, x2), w);
    o = shflx(x3, h); x3 = up ? cadd(x3, o) : cmul(csub(o, x3), w);
  }
  {
    bool up = (l & 1) == 0;
    float2 o;
    o = shflx(x0, 1); x0 = up ? cadd(x0, o) : csub(o, x0);
    o = shflx(x1, 1); x1 = up ? cadd(x1, o) : csub(o, x1);
    o = shflx(x2, 1); x2 = up ? cadd(x2, o) : csub(o, x2);
    o = shflx(x3, 1); x3 = up ? cadd(x3, o) : csub(o, x3);
  }
}

__device__ __forceinline__ void fft256_inv_crop(float2& x0, float2& x1,
                                                float2& x2, float2& x3,
                                                const Tw& t, int l){
  {
    bool up = (l & 1) == 0;
    float2 o;
    o = shflx(x0, 1); x0 = up ? cadd(x0, o) : csub(o, x0);
    o = shflx(x1, 1); x1 = up ? cadd(x1, o) : csub(o, x1);
    o = shflx(x2, 1); x2 = up ? cadd(x2, o) : csub(o, x2);
    o = shflx(x3, 1); x3 = up ? cadd(x3, o) : csub(o, x3);
  }
  const int hs[5] = {32,16,8,4,2};
#pragma unroll
  for (int i = 4; i >= 0; --i){
    int h = hs[i];
    bool up = (l & h) == 0;
    float2 w = make_float2(t.wc[i].x, -t.wc[i].y);
    float2 o;
    o = shflx(x0, h); x0 = up ? cadd(x0, cmul(w, o)) : csub(o, cmul(w, x0));
    o = shflx(x1, h); x1 = up ? cadd(x1, cmul(w, o)) : csub(o, cmul(w, x1));
    o = shflx(x2, h); x2 = up ? cadd(x2, cmul(w, o)) : csub(o, cmul(w, x2));
    o = shflx(x3, h); x3 = up ? cadd(x3, cmul(w, o)) : csub(o, cmul(w, x3));
  }
  {
    float2 w = make_float2(t.w64.x, -t.w64.y);
    float2 t0 = cmul(w, x1); x1 = csub(x0, t0); x0 = cadd(x0, t0);
    float2 t1 = cmul(w, x3); x3 = csub(x2, t1); x2 = cadd(x2, t1);
  }
  {
    float2 wa = make_float2(t.w128a.x, -t.w128a.y);
    float2 wb = make_float2(t.w128b.x, -t.w128b.y);
    x0 = cadd(x0, cmul(wa, x2));
    x1 = cadd(x1, cmul(wb, x3));
  }
}

// Compressed natural-bin -> LDS-row map. Bins come out of the DIF as
// nb = 4*br6(l) + {0,2,1,3}; cmap keeps column accesses 2-way (free).
// cmap(nb) = (nb>>2) + 33*(nb&3), rows 0..130.
// ---------------------------------------------------------------------------
// kprep: one block per channel c. MLP -> k, col FFT, row FFT -> Khat[c][u][v]
// (u = natural bin 0..128, v = DIF storage position 0..255). fp32 LDS.
// ---------------------------------------------------------------------------
__global__ __launch_bounds__(512) void kprep(const float* __restrict__ W1,
                                             const float* __restrict__ b1,
                                             const float* __restrict__ W2,
                                             const float* __restrict__ b2,
                                             float2* __restrict__ Khat){
  __shared__ float sRe[131*129];
  __shared__ float sIm[131*129];
  const int S = 129;
  int t = threadIdx.x, l = t & 63, w = t >> 6;
  int c = blockIdx.x;
  Tw tw; tw_init(tw, l);
  int r6 = __brev((unsigned)l) >> 26;

  float w1y[16], w1x[16], bb1[16], w2r[16];
#pragma unroll
  for (int h = 0; h < 16; ++h){
    w1y[h] = W1[h]; w1x[h] = W1[16+h]; bb1[h] = b1[h]; w2r[h] = W2[h*CC + c];
  }
  float bb2 = b2[c];
  for (int i = t; i < HH*WW; i += 512){
    int p = i >> 7, q = i & 127;
    float gy = p * (1.0f/127.0f), gx = q * (1.0f/127.0f);
    float acc = bb2;
#pragma unroll
    for (int h = 0; h < 16; ++h){
      float hv = fmaxf(gy*w1y[h] + gx*w1x[h] + bb1[h], 0.0f);
      acc += hv * w2r[h];
    }
    sRe[p*S + q] = acc;
  }
  __syncthreads();
  // column forward FFTs (128 cols / 8 waves)
  for (int qi = 0; qi < 16; ++qi){
    int q = w*16 + qi;
    float2 x0 = make_float2(sRe[l*S + q], 0.f);
    float2 x1 = make_float2(sRe[(l+64)*S + q], 0.f);
    float2 x2, x3;
    fft256_fwd_padded(x0, x1, x2, x3, tw, l);
    if (r6 <= 32){ sRe[r6*S+q] = x0.x; sIm[r6*S+q] = x0.y; }          // nb=4r6
    if (r6 <= 31){
      sRe[(33+r6)*S+q] = x2.x; sIm[(33+r6)*S+q] = x2.y;               // nb=4r6+1
      sRe[(66+r6)*S+q] = x1.x; sIm[(66+r6)*S+q] = x1.y;               // nb=4r6+2
      sRe[(99+r6)*S+q] = x3.x; sIm[(99+r6)*S+q] = x3.y;               // nb=4r6+3
    }
  }
  __syncthreads();
  // row forward FFTs -> Khat
  for (int u = w; u < NF; u += 8){
    int pr = (u >> 2) + 33*(u & 3);
    float2 x0 = make_float2(sRe[pr*S + l],      sIm[pr*S + l]);
    float2 x1 = make_float2(sRe[pr*S + 64 + l], sIm[pr*S + 64 + l]);
    float2 x2, x3;
    fft256_fwd_padded(x0, x1, x2, x3, tw, l);
    float2* dst = Khat + ((size_t)c*NF + u)*FN;
    dst[l] = x0; dst[64+l] = x1; dst[128+l] = x2; dst[192+l] = x3;
  }
}

// ---------------------------------------------------------------------------
// fused_conv: one block per (b,c) image. Whole 2D FFT-conv in LDS.
// Spectra: fp16 planes (stride 130, conflict-free). x and y stored exactly
// by splitting fp32 bits across the two ushort planes.
// ---------------------------------------------------------------------------
__global__ __launch_bounds__(512) void fused_conv(const float* __restrict__ x,
                                                  const float2* __restrict__ Khat,
                                                  float* __restrict__ out){
  __shared__ unsigned short hRe[131*130];
  __shared__ unsigned short hIm[131*130];
  const int S = 130;
  int t = threadIdx.x, l = t & 63, w = t >> 6;
  int blk = blockIdx.x;
  int c = blk >> 4, b = blk & 15;        // 16 consecutive blocks share c (Khat L2 reuse)
  const float* xp = x   + ((size_t)b*CC + c)*(HH*WW);
  float*       yp = out + ((size_t)b*CC + c)*(HH*WW);
  Tw tw; tw_init(tw, l);
  int r6 = __brev((unsigned)l) >> 26;

  // 1) x -> planes (exact fp32 split: hi16 in hRe, lo16 in hIm)
  for (int i = t; i < HH*WW; i += 512){
    int p = i >> 7, q = i & 127;
    unsigned int ub = __float_as_uint(xp[i]);
    hRe[p*S + q] = (unsigned short)(ub >> 16);
    hIm[p*S + q] = (unsigned short)(ub & 0xffffu);
  }
  __syncthreads();
  // 2) column forward FFTs; store bins (fp16) via cmap
  for (int qi = 0; qi < 16; ++qi){
    int q = w*16 + qi;
    unsigned int u0 = ((unsigned int)hRe[l*S+q] << 16)      | hIm[l*S+q];
    unsigned int u1 = ((unsigned int)hRe[(l+64)*S+q] << 16) | hIm[(l+64)*S+q];
    float2 x0 = make_float2(__uint_as_float(u0), 0.f);
    float2 x1 = make_float2(__uint_as_float(u1), 0.f);
    float2 x2, x3;
    fft256_fwd_padded(x0, x1, x2, x3, tw, l);
    if (r6 <= 32){ hRe[r6*S+q] = f2h(x0.x); hIm[r6*S+q] = f2h(x0.y); }
    if (r6 <= 31){
      hRe[(33+r6)*S+q] = f2h(x2.x); hIm[(33+r6)*S+q] = f2h(x2.y);
      hRe[(66+r6)*S+q] = f2h(x1.x); hIm[(66+r6)*S+q] = f2h(x1.y);
      hRe[(99+r6)*S+q] = f2h(x3.x); hIm[(99+r6)*S+q] = f2h(x3.y);
    }
  }
  __syncthreads();
  // 3) row conv: fwd -> x Khat -> inv+crop, in place (scaled 2^-10)
  for (int u = w; u < NF; u += 8){
    int pr = (u >> 2) + 33*(u & 3);
    float2 x0 = make_float2(h2f(hRe[pr*S + l]),      h2f(hIm[pr*S + l]));
    float2 x1 = make_float2(h2f(hRe[pr*S + 64 + l]), h2f(hIm[pr*S + 64 + l]));
    float2 x2, x3;
    fft256_fwd_padded(x0, x1, x2, x3, tw, l);
    const float2* kp = Khat + ((size_t)c*NF + u)*FN;
    x0 = cmul(x0, kp[l]);
    x1 = cmul(x1, kp[64 + l]);
    x2 = cmul(x2, kp[128 + l]);
    x3 = cmul(x3, kp[192 + l]);
    fft256_inv_crop(x0, x1, x2, x3, tw, l);
    hRe[pr*S + l]      = f2h(x0.x * SCL_DN); hIm[pr*S + l]      = f2h(x0.y * SCL_DN);
    hRe[pr*S + 64 + l] = f2h(x1.x * SCL_DN); hIm[pr*S + 64 + l] = f2h(x1.y * SCL_DN);
  }
  __syncthreads();
  // 4) column inverse (Hermitian gather by natural bin) + crop -> y (exact fp32 split)
  for (int qi = 0; qi < 16; ++qi){
    int q = w*16 + qi;
    float2 x0, x1, x2, x3;
    if (r6 <= 32){ x0 = make_float2(h2f(hRe[r6*S+q]),        h2f(hIm[r6*S+q])); }          // nb=4r6
    else         { x0 = make_float2(h2f(hRe[(64-r6)*S+q]),  -h2f(hIm[(64-r6)*S+q])); }     // conj(256-nb)
    if (r6 <= 31){ x1 = make_float2(h2f(hRe[(66+r6)*S+q]),   h2f(hIm[(66+r6)*S+q])); }     // nb=4r6+2
    else         { x1 = make_float2(h2f(hRe[(129-r6)*S+q]), -h2f(hIm[(129-r6)*S+q])); }
    if (r6 <= 31){ x2 = make_float2(h2f(hRe[(33+r6)*S+q]),   h2f(hIm[(33+r6)*S+q])); }     // nb=4r6+1
    else         { x2 = make_float2(h2f(hRe[(162-r6)*S+q]), -h2f(hIm[(162-r6)*S+q])); }
    if (r6 <= 31){ x3 = make_float2(h2f(hRe[(99+r6)*S+q]),   h2f(hIm[(99+r6)*S+q])); }     // nb=4r6+3
    else         { x3 = make_float2(h2f(hRe[(96-r6)*S+q]),  -h2f(hIm[(96-r6)*S+q])); }
    fft256_inv_crop(x0, x1, x2, x3, tw, l);
    unsigned int ua = __float_as_uint(x0.x * SCL_UP);
    unsigned int ub = __float_as_uint(x1.x * SCL_UP);
    hRe[l*S + q]      = (unsigned short)(ua >> 16);
    hIm[l*S + q]      = (unsigned short)(ua & 0xffffu);
    hRe[(l+64)*S + q] = (unsigned short)(ub >> 16);
    hIm[(l+64)*S + q] = (unsigned short)(ub & 0xffffu);
  }
  __syncthreads();
  // 5) out = y + x (coalesced)
  for (int i = t; i < HH*WW; i += 512){
    int p = i >> 7, q = i & 127;
    unsigned int ub = ((unsigned int)hRe[p*S + q] << 16) | hIm[p*S + q];
    yp[i] = __uint_as_float(ub) + xp[i];
  }
}

// ---------------------------------------------------------------------------
// Host launcher
// ---------------------------------------------------------------------------
extern "C" void kernel_launch(void* const* d_in, const int* in_sizes, int n_in,
                              void* d_out, int out_size, void* d_ws, size_t ws_size,
                              hipStream_t stream) {
  const float* x  = (const float*)d_in[0];
  const float* W1 = (const float*)d_in[1];
  const float* b1 = (const float*)d_in[2];
  const float* W2 = (const float*)d_in[3];
  const float* b2 = (const float*)d_in[4];
  float* out = (float*)d_out;

  float2* Khat = (float2*)d_ws;   // CC*NF*FN complex = 25.4 MB

  kprep<<<CC, 512, 0, stream>>>(W1, b1, W2, b2, Khat);
  fused_conv<<<CC * BB, 512, 0, stream>>>(x, Khat, out);
}